// Round 1
// baseline (1195.600 us; speedup 1.0000x reference)
//
#include <hip/hip_runtime.h>
#include <hip/hip_bf16.h>

#define T_TOK 8192
#define D_DIM 1024
#define F_DIM 4096
#define E_NUM 8

typedef short s16x8 __attribute__((ext_vector_type(8)));
typedef float f32x4 __attribute__((ext_vector_type(4)));
typedef unsigned short u16x8 __attribute__((ext_vector_type(8)));

__device__ __forceinline__ unsigned short f2bf(float f) {
  union { float f; unsigned int u; } v; v.f = f;
  unsigned int u = v.u;
  return (unsigned short)((u + 0x7FFFu + ((u >> 16) & 1u)) >> 16);  // RNE
}

__device__ __forceinline__ void async16(const void* g, void* l) {
  __builtin_amdgcn_global_load_lds((const __attribute__((address_space(1))) void*)g,
                                   (__attribute__((address_space(3))) void*)l, 16, 0, 0);
}

// ---------------- RMSNorm + router (fp32) + top-2 compaction ----------------
__global__ __launch_bounds__(256) void norm_router_kernel(
    const float* __restrict__ hs, const float* __restrict__ nw,
    const float* __restrict__ gw, unsigned short* __restrict__ xb,
    float* __restrict__ logits_out, int* __restrict__ cnt,
    int* __restrict__ ilist, float* __restrict__ wlist) {
  int t = blockIdx.x;
  int tid = threadIdx.x;
  int lane = tid & 63, wid = tid >> 6;
  float4 v = ((const float4*)(hs + (size_t)t * D_DIM))[tid];
  float ss = v.x * v.x + v.y * v.y + v.z * v.z + v.w * v.w;
#pragma unroll
  for (int o = 32; o > 0; o >>= 1) ss += __shfl_xor(ss, o);
  __shared__ float red[4];
  __shared__ float pl[4][8];
  if (lane == 0) red[wid] = ss;
  __syncthreads();
  float ms = (red[0] + red[1] + red[2] + red[3]) * (1.0f / 1024.0f);
  float rs = rsqrtf(ms + 1e-6f);
  float4 wv = ((const float4*)nw)[tid];
  float x0 = v.x * rs * wv.x, x1 = v.y * rs * wv.y;
  float x2 = v.z * rs * wv.z, x3 = v.w * rs * wv.w;
  ((ushort4*)(xb + (size_t)t * D_DIM))[tid] =
      make_ushort4(f2bf(x0), f2bf(x1), f2bf(x2), f2bf(x3));
  float p[8];
#pragma unroll
  for (int e = 0; e < 8; ++e) {
    float4 g = ((const float4*)(gw + (size_t)e * D_DIM))[tid];
    p[e] = x0 * g.x + x1 * g.y + x2 * g.z + x3 * g.w;
  }
#pragma unroll
  for (int e = 0; e < 8; ++e) {
#pragma unroll
    for (int o = 32; o > 0; o >>= 1) p[e] += __shfl_xor(p[e], o);
  }
  if (lane == 0) {
#pragma unroll
    for (int e = 0; e < 8; ++e) pl[wid][e] = p[e];
  }
  __syncthreads();
  if (tid == 0) {
    float l[8];
#pragma unroll
    for (int e = 0; e < 8; ++e) {
      l[e] = pl[0][e] + pl[1][e] + pl[2][e] + pl[3][e];
      logits_out[(size_t)t * 8 + e] = l[e];
    }
    int i0 = 0; float b0 = l[0];
#pragma unroll
    for (int e = 1; e < 8; ++e) if (l[e] > b0) { b0 = l[e]; i0 = e; }
    int i1 = (i0 == 0) ? 1 : 0; float b1 = l[i1];
#pragma unroll
    for (int e = 0; e < 8; ++e) if (e != i0 && l[e] > b1) { b1 = l[e]; i1 = e; }
    float wa = 1.0f / (1.0f + __expf(b1 - b0));
    float wb = 1.0f / (1.0f + __expf(b0 - b1));
    int p0 = atomicAdd(&cnt[i0], 1);
    ilist[i0 * T_TOK + p0] = t * 2;     wlist[i0 * T_TOK + p0] = wa;
    int p1 = atomicAdd(&cnt[i1], 1);
    ilist[i1 * T_TOK + p1] = t * 2 + 1; wlist[i1 * T_TOK + p1] = wb;
  }
}

// ---------------- weight f32 [R][C] -> bf16 [C][R] transpose-convert ----------------
__global__ __launch_bounds__(256) void transpose_cvt_kernel(
    const float* __restrict__ w1, const float* __restrict__ w3,
    const float* __restrict__ w2, unsigned short* __restrict__ w1t,
    unsigned short* __restrict__ w3t, unsigned short* __restrict__ w2t) {
  __shared__ unsigned short tileS[64][72];  // [c-local][r-local], padded
  int bx = blockIdx.x;
  int tensor = bx >> 13;
  int e = (bx >> 10) & 7;
  int tl = bx & 1023;
  const float* src; unsigned short* dst; int R, C, tr, tc;
  if (tensor == 0) {
    src = w1 + (size_t)e * D_DIM * F_DIM; dst = w1t + (size_t)e * F_DIM * D_DIM;
    R = D_DIM; C = F_DIM; tr = tl >> 6; tc = tl & 63;
  } else if (tensor == 1) {
    src = w3 + (size_t)e * D_DIM * F_DIM; dst = w3t + (size_t)e * F_DIM * D_DIM;
    R = D_DIM; C = F_DIM; tr = tl >> 6; tc = tl & 63;
  } else {
    src = w2 + (size_t)e * F_DIM * D_DIM; dst = w2t + (size_t)e * D_DIM * F_DIM;
    R = F_DIM; C = D_DIM; tr = tl >> 4; tc = tl & 15;
  }
  int r0 = tr * 64, c0 = tc * 64;
  int tid = threadIdx.x;
  int rr = tid >> 4, ccb = (tid & 15) * 4;
#pragma unroll
  for (int i = 0; i < 4; ++i) {
    int r = rr + i * 16;
    float4 v = *(const float4*)(src + (size_t)(r0 + r) * C + c0 + ccb);
    tileS[ccb + 0][r] = f2bf(v.x);
    tileS[ccb + 1][r] = f2bf(v.y);
    tileS[ccb + 2][r] = f2bf(v.z);
    tileS[ccb + 3][r] = f2bf(v.w);
  }
  __syncthreads();
  int row = tid >> 2, col = (tid & 3) * 16;
  unsigned short* dp = dst + (size_t)(c0 + row) * R + r0 + col;
  u16x8 v0, v1;
#pragma unroll
  for (int j = 0; j < 8; ++j) { v0[j] = tileS[row][col + j]; v1[j] = tileS[row][col + 8 + j]; }
  *(u16x8*)dp = v0;
  *(u16x8*)(dp + 8) = v1;
}

// ---------------- GEMM1: H = silu(Xe@W1e) * (Xe@W3e), gathered rows ----------------
__global__ __launch_bounds__(256, 2) void gemm1_kernel(
    const unsigned short* __restrict__ xb, const unsigned short* __restrict__ w1t,
    const unsigned short* __restrict__ w3t, unsigned short* __restrict__ H,
    const int* __restrict__ cnt, const int* __restrict__ ilist) {
  int e = blockIdx.x >> 6;
  int rt = blockIdx.x & 63;
  int ne = cnt[e];
  int r0 = rt * 128;
  if (r0 >= ne) return;
  int n0 = blockIdx.y * 128;
  __shared__ __align__(16) unsigned short As[128 * 64];
  __shared__ __align__(16) unsigned short B1s[128 * 64];
  __shared__ __align__(16) unsigned short B3s[128 * 64];
  __shared__ int toks[128];
  int tid = threadIdx.x, lane = tid & 63, w = tid >> 6;
  if (tid < 128) toks[tid] = ilist[e * T_TOK + min(r0 + tid, ne - 1)];
  __syncthreads();
  const unsigned short* b1b = w1t + ((size_t)e * F_DIM + n0) * D_DIM;
  const unsigned short* b3b = w3t + ((size_t)e * F_DIM + n0) * D_DIM;
  f32x4 acc1[4][4] = {};
  f32x4 acc3[4][4] = {};
  int wr = w >> 1, wc = w & 1;
  for (int k0 = 0; k0 < D_DIM; k0 += 64) {
    __syncthreads();
#pragma unroll
    for (int i = 0; i < 4; ++i) {
      int inst = w * 4 + i;
      int rowl = inst * 8 + (lane >> 3);
      int chunk = (lane & 7) ^ (rowl & 7);   // inverse-swizzled source (rule #21)
      int coff = k0 + chunk * 8;
      async16(xb + (size_t)(toks[rowl] >> 1) * D_DIM + coff, As + inst * 512);
      async16(b1b + (size_t)rowl * D_DIM + coff, B1s + inst * 512);
      async16(b3b + (size_t)rowl * D_DIM + coff, B3s + inst * 512);
    }
    __syncthreads();
#pragma unroll
    for (int ks = 0; ks < 2; ++ks) {
      int lc = ks * 4 + (lane >> 4);
      s16x8 a[4], b[4];
#pragma unroll
      for (int m = 0; m < 4; ++m) {
        int row = wr * 64 + m * 16 + (lane & 15);
        a[m] = *(const s16x8*)(As + row * 64 + ((lc ^ (row & 7)) * 8));
      }
#pragma unroll
      for (int n = 0; n < 4; ++n) {
        int row = wc * 64 + n * 16 + (lane & 15);
        b[n] = *(const s16x8*)(B1s + row * 64 + ((lc ^ (row & 7)) * 8));
      }
#pragma unroll
      for (int m = 0; m < 4; ++m)
#pragma unroll
        for (int n = 0; n < 4; ++n)
          acc1[m][n] = __builtin_amdgcn_mfma_f32_16x16x32_bf16(a[m], b[n], acc1[m][n], 0, 0, 0);
#pragma unroll
      for (int n = 0; n < 4; ++n) {
        int row = wc * 64 + n * 16 + (lane & 15);
        b[n] = *(const s16x8*)(B3s + row * 64 + ((lc ^ (row & 7)) * 8));
      }
#pragma unroll
      for (int m = 0; m < 4; ++m)
#pragma unroll
        for (int n = 0; n < 4; ++n)
          acc3[m][n] = __builtin_amdgcn_mfma_f32_16x16x32_bf16(a[m], b[n], acc3[m][n], 0, 0, 0);
    }
  }
  int g4 = lane >> 4, cl = lane & 15;
#pragma unroll
  for (int m = 0; m < 4; ++m) {
#pragma unroll
    for (int j = 0; j < 4; ++j) {
      int rloc = wr * 64 + m * 16 + g4 * 4 + j;
      if (r0 + rloc < ne) {
        unsigned short* hp = H + (size_t)toks[rloc] * F_DIM + n0 + wc * 64 + cl;
#pragma unroll
        for (int n = 0; n < 4; ++n) {
          float c1 = acc1[m][n][j], c3 = acc3[m][n][j];
          float h = c1 / (1.0f + __expf(-c1)) * c3;
          hp[n * 16] = f2bf(h);
        }
      }
    }
  }
}

// ---------------- GEMM2: out += w * (He @ W2e), atomic scatter ----------------
__global__ __launch_bounds__(256, 2) void gemm2_kernel(
    const unsigned short* __restrict__ H, const unsigned short* __restrict__ w2t,
    const int* __restrict__ cnt, const int* __restrict__ ilist,
    const float* __restrict__ wlist, float* __restrict__ out) {
  int e = blockIdx.x >> 6;
  int rt = blockIdx.x & 63;
  int ne = cnt[e];
  int r0 = rt * 128;
  if (r0 >= ne) return;
  int n0 = blockIdx.y * 128;
  __shared__ __align__(16) unsigned short As[128 * 64];
  __shared__ __align__(16) unsigned short Bs[128 * 64];
  __shared__ int toks[128];
  __shared__ float wts[128];
  int tid = threadIdx.x, lane = tid & 63, w = tid >> 6;
  if (tid < 128) {
    int idx = e * T_TOK + min(r0 + tid, ne - 1);
    toks[tid] = ilist[idx];
    wts[tid] = wlist[idx];
  }
  __syncthreads();
  const unsigned short* bb = w2t + ((size_t)e * D_DIM + n0) * F_DIM;
  f32x4 acc[4][4] = {};
  int wr = w >> 1, wc = w & 1;
  for (int k0 = 0; k0 < F_DIM; k0 += 64) {
    __syncthreads();
#pragma unroll
    for (int i = 0; i < 4; ++i) {
      int inst = w * 4 + i;
      int rowl = inst * 8 + (lane >> 3);
      int chunk = (lane & 7) ^ (rowl & 7);
      int coff = k0 + chunk * 8;
      async16(H + (size_t)toks[rowl] * F_DIM + coff, As + inst * 512);
      async16(bb + (size_t)rowl * F_DIM + coff, Bs + inst * 512);
    }
    __syncthreads();
#pragma unroll
    for (int ks = 0; ks < 2; ++ks) {
      int lc = ks * 4 + (lane >> 4);
      s16x8 a[4], b[4];
#pragma unroll
      for (int m = 0; m < 4; ++m) {
        int row = wr * 64 + m * 16 + (lane & 15);
        a[m] = *(const s16x8*)(As + row * 64 + ((lc ^ (row & 7)) * 8));
      }
#pragma unroll
      for (int n = 0; n < 4; ++n) {
        int row = wc * 64 + n * 16 + (lane & 15);
        b[n] = *(const s16x8*)(Bs + row * 64 + ((lc ^ (row & 7)) * 8));
      }
#pragma unroll
      for (int m = 0; m < 4; ++m)
#pragma unroll
        for (int n = 0; n < 4; ++n)
          acc[m][n] = __builtin_amdgcn_mfma_f32_16x16x32_bf16(a[m], b[n], acc[m][n], 0, 0, 0);
    }
  }
  int g4 = lane >> 4, cl = lane & 15;
#pragma unroll
  for (int m = 0; m < 4; ++m) {
#pragma unroll
    for (int j = 0; j < 4; ++j) {
      int rloc = wr * 64 + m * 16 + g4 * 4 + j;
      if (r0 + rloc < ne) {
        int tok = toks[rloc] >> 1;
        float ww = wts[rloc];
        float* op = out + (size_t)tok * D_DIM + n0 + wc * 64 + cl;
#pragma unroll
        for (int n = 0; n < 4; ++n)
          unsafeAtomicAdd(op + n * 16, ww * acc[m][n][j]);
      }
    }
  }
}

extern "C" void kernel_launch(void* const* d_in, const int* in_sizes, int n_in,
                              void* d_out, int out_size, void* d_ws, size_t ws_size,
                              hipStream_t stream) {
  const float* hs = (const float*)d_in[0];
  const float* nw = (const float*)d_in[1];
  const float* gw = (const float*)d_in[2];
  const float* w1 = (const float*)d_in[3];
  const float* w3 = (const float*)d_in[4];
  const float* w2 = (const float*)d_in[5];
  float* out = (float*)d_out;
  float* logits_out = out + (size_t)T_TOK * D_DIM;

  char* ws = (char*)d_ws;
  unsigned short* xb  = (unsigned short*)(ws);                 // 16 MiB bf16 x
  unsigned short* w1t = (unsigned short*)(ws + 16777216ull);   // 64 MiB [E][F][D] bf16
  unsigned short* w3t = (unsigned short*)(ws + 83886080ull);   // 64 MiB
  unsigned short* w2t = (unsigned short*)(ws + 150994944ull);  // 64 MiB [E][D][F] bf16
  unsigned short* H   = (unsigned short*)(ws + 218103808ull);  // 128 MiB [2T][F] bf16
  int*   ilist = (int*)(ws + 352321536ull);                    // [E][T] int
  float* wlist = (float*)(ws + 352583680ull);                  // [E][T] f32
  int*   cnt   = (int*)(ws + 352845824ull);                    // [E] int

  hipMemsetAsync(d_out, 0, (size_t)out_size * sizeof(float), stream);
  hipMemsetAsync(cnt, 0, E_NUM * sizeof(int), stream);
  norm_router_kernel<<<T_TOK, 256, 0, stream>>>(hs, nw, gw, xb, logits_out, cnt, ilist, wlist);
  transpose_cvt_kernel<<<3 * E_NUM * 1024, 256, 0, stream>>>(w1, w3, w2, w1t, w3t, w2t);
  gemm1_kernel<<<dim3(E_NUM * 64, F_DIM / 128), 256, 0, stream>>>(xb, w1t, w3t, H, cnt, ilist);
  gemm2_kernel<<<dim3(E_NUM * 64, D_DIM / 128), 256, 0, stream>>>(H, w2t, cnt, ilist, wlist, out);
}

// Round 2
// 966.698 us; speedup vs baseline: 1.2368x; 1.2368x over previous
//
#include <hip/hip_runtime.h>
#include <hip/hip_bf16.h>

#define T_TOK 8192
#define D_DIM 1024
#define F_DIM 4096
#define E_NUM 8

typedef short s16x8 __attribute__((ext_vector_type(8)));
typedef float f32x4 __attribute__((ext_vector_type(4)));
typedef unsigned short u16x8 __attribute__((ext_vector_type(8)));

__device__ __forceinline__ unsigned short f2bf(float f) {
  union { float f; unsigned int u; } v; v.f = f;
  unsigned int u = v.u;
  return (unsigned short)((u + 0x7FFFu + ((u >> 16) & 1u)) >> 16);  // RNE
}

__device__ __forceinline__ void async16(const void* g, void* l) {
  __builtin_amdgcn_global_load_lds((const __attribute__((address_space(1))) void*)g,
                                   (__attribute__((address_space(3))) void*)l, 16, 0, 0);
}

// ---------------- RMSNorm + router (fp32) + top-2 compaction ----------------
__global__ __launch_bounds__(256) void norm_router_kernel(
    const float* __restrict__ hs, const float* __restrict__ nw,
    const float* __restrict__ gw, unsigned short* __restrict__ xb,
    float* __restrict__ logits_out, int* __restrict__ cnt,
    int* __restrict__ ilist, float* __restrict__ wlist) {
  int t = blockIdx.x;
  int tid = threadIdx.x;
  int lane = tid & 63, wid = tid >> 6;
  float4 v = ((const float4*)(hs + (size_t)t * D_DIM))[tid];
  float ss = v.x * v.x + v.y * v.y + v.z * v.z + v.w * v.w;
#pragma unroll
  for (int o = 32; o > 0; o >>= 1) ss += __shfl_xor(ss, o);
  __shared__ float red[4];
  __shared__ float pl[4][8];
  if (lane == 0) red[wid] = ss;
  __syncthreads();
  float ms = (red[0] + red[1] + red[2] + red[3]) * (1.0f / 1024.0f);
  float rs = rsqrtf(ms + 1e-6f);
  float4 wv = ((const float4*)nw)[tid];
  float x0 = v.x * rs * wv.x, x1 = v.y * rs * wv.y;
  float x2 = v.z * rs * wv.z, x3 = v.w * rs * wv.w;
  ((ushort4*)(xb + (size_t)t * D_DIM))[tid] =
      make_ushort4(f2bf(x0), f2bf(x1), f2bf(x2), f2bf(x3));
  float p[8];
#pragma unroll
  for (int e = 0; e < 8; ++e) {
    float4 g = ((const float4*)(gw + (size_t)e * D_DIM))[tid];
    p[e] = x0 * g.x + x1 * g.y + x2 * g.z + x3 * g.w;
  }
#pragma unroll
  for (int e = 0; e < 8; ++e) {
#pragma unroll
    for (int o = 32; o > 0; o >>= 1) p[e] += __shfl_xor(p[e], o);
  }
  if (lane == 0) {
#pragma unroll
    for (int e = 0; e < 8; ++e) pl[wid][e] = p[e];
  }
  __syncthreads();
  if (tid == 0) {
    float l[8];
#pragma unroll
    for (int e = 0; e < 8; ++e) {
      l[e] = pl[0][e] + pl[1][e] + pl[2][e] + pl[3][e];
      logits_out[(size_t)t * 8 + e] = l[e];
    }
    int i0 = 0; float b0 = l[0];
#pragma unroll
    for (int e = 1; e < 8; ++e) if (l[e] > b0) { b0 = l[e]; i0 = e; }
    int i1 = (i0 == 0) ? 1 : 0; float b1 = l[i1];
#pragma unroll
    for (int e = 0; e < 8; ++e) if (e != i0 && l[e] > b1) { b1 = l[e]; i1 = e; }
    float wa = 1.0f / (1.0f + __expf(b1 - b0));
    float wb = 1.0f / (1.0f + __expf(b0 - b1));
    int p0 = atomicAdd(&cnt[i0], 1);
    ilist[i0 * T_TOK + p0] = t * 2;     wlist[i0 * T_TOK + p0] = wa;
    int p1 = atomicAdd(&cnt[i1], 1);
    ilist[i1 * T_TOK + p1] = t * 2 + 1; wlist[i1 * T_TOK + p1] = wb;
  }
}

// ---- weight f32 -> bf16 transpose. w1/w3 -> interleaved w13t[e][ft][128][D];
// ---- w2 -> w2t[e][D][F]
__global__ __launch_bounds__(256) void transpose_cvt_kernel(
    const float* __restrict__ w1, const float* __restrict__ w3,
    const float* __restrict__ w2, unsigned short* __restrict__ w13t,
    unsigned short* __restrict__ w2t) {
  __shared__ unsigned short tileS[64][72];  // [c-local][r-local], padded
  int bx = blockIdx.x;
  int tensor = bx >> 13;
  int e = (bx >> 10) & 7;
  int tl = bx & 1023;
  const float* src; int C, tr, tc;
  if (tensor == 0) {
    src = w1 + (size_t)e * D_DIM * F_DIM; C = F_DIM; tr = tl >> 6; tc = tl & 63;
  } else if (tensor == 1) {
    src = w3 + (size_t)e * D_DIM * F_DIM; C = F_DIM; tr = tl >> 6; tc = tl & 63;
  } else {
    src = w2 + (size_t)e * F_DIM * D_DIM; C = D_DIM; tr = tl >> 4; tc = tl & 15;
  }
  int r0 = tr * 64, c0 = tc * 64;
  int tid = threadIdx.x;
  int rr = tid >> 4, ccb = (tid & 15) * 4;
#pragma unroll
  for (int i = 0; i < 4; ++i) {
    int r = rr + i * 16;
    float4 v = *(const float4*)(src + (size_t)(r0 + r) * C + c0 + ccb);
    tileS[ccb + 0][r] = f2bf(v.x);
    tileS[ccb + 1][r] = f2bf(v.y);
    tileS[ccb + 2][r] = f2bf(v.z);
    tileS[ccb + 3][r] = f2bf(v.w);
  }
  __syncthreads();
  int row = tid >> 2, col = (tid & 3) * 16;
  unsigned short* dp;
  if (tensor < 2) {
    int f = c0 + row;
    int prow = ((f >> 6) * 128) + (f & 63) + (tensor == 1 ? 64 : 0);
    dp = w13t + ((size_t)e * 8192 + prow) * D_DIM + r0 + col;
  } else {
    dp = w2t + ((size_t)e * D_DIM + c0 + row) * F_DIM + r0 + col;
  }
  u16x8 v0, v1;
#pragma unroll
  for (int j = 0; j < 8; ++j) { v0[j] = tileS[row][col + j]; v1[j] = tileS[row][col + 8 + j]; }
  *(u16x8*)dp = v0;
  *(u16x8*)(dp + 8) = v1;
}

// ---------------- GEMM1: H = silu(Xe@W1e) * (Xe@W3e), 2-phase pipelined ----------------
__global__ __launch_bounds__(256, 3) void gemm1_kernel(
    const unsigned short* __restrict__ xb, const unsigned short* __restrict__ w13t,
    unsigned short* __restrict__ H, const int* __restrict__ cnt,
    const int* __restrict__ ilist) {
  int flat = blockIdx.x;                    // 32768 blocks
  int W = (flat & 7) * 4096 + (flat >> 3);  // XCD-contiguous work chunks
  int rt = W & 63;
  int p = W >> 6;
  int ft = p & 63;
  int e = p >> 6;                           // expert == XCD
  int ne = cnt[e];
  int r0 = rt * 128;
  if (r0 >= ne) return;
  __shared__ __align__(16) unsigned short As[2][128 * 32];
  __shared__ __align__(16) unsigned short Bs[2][128 * 32];
  __shared__ int toks[128];
  int tid = threadIdx.x, lane = tid & 63, w = tid >> 6;
  if (tid < 128) toks[tid] = ilist[e * T_TOK + min(r0 + tid, ne - 1)];
  __syncthreads();
  const unsigned short* bpanel = w13t + ((size_t)(e * 64 + ft) * 128) * D_DIM;
  // staging addresses (rows this wave stages: w*32+[0..31], 2 calls of 16 rows)
  int sr0 = w * 32 + (lane >> 2);
  int sr1 = sr0 + 16;
  int ch0 = (((lane & 3) ^ ((sr0 >> 1) & 3)) * 8);
  int ch1 = (((lane & 3) ^ ((sr1 >> 1) & 3)) * 8);
  const unsigned short* asrc0 = xb + (size_t)(toks[sr0] >> 1) * D_DIM + ch0;
  const unsigned short* asrc1 = xb + (size_t)(toks[sr1] >> 1) * D_DIM + ch1;
  const unsigned short* bsrc0 = bpanel + (size_t)sr0 * D_DIM + ch0;
  const unsigned short* bsrc1 = bpanel + (size_t)sr1 * D_DIM + ch1;
  int d0 = (w * 2 + 0) * 512 + lane * 8;
  int d1 = (w * 2 + 1) * 512 + lane * 8;
  f32x4 acc[2][8] = {};
  // prologue: stage k0=0 into buf 0
  async16(asrc0, &As[0][d0]); async16(bsrc0, &Bs[0][d0]);
  async16(asrc1, &As[0][d1]); async16(bsrc1, &Bs[0][d1]);
  __syncthreads();  // vmcnt(0) drain + barrier
  int cur = 0;
  for (int k0 = 0; k0 < D_DIM; k0 += 32) {
    int nk = k0 + 32;
    if (nk < D_DIM) {  // issue next-tile loads BEFORE compute (2-phase)
      async16(asrc0 + nk, &As[cur ^ 1][d0]); async16(bsrc0 + nk, &Bs[cur ^ 1][d0]);
      async16(asrc1 + nk, &As[cur ^ 1][d1]); async16(bsrc1 + nk, &Bs[cur ^ 1][d1]);
    }
    int lc = lane >> 4;
    s16x8 a[2], b[8];
#pragma unroll
    for (int m = 0; m < 2; ++m) {
      int row = w * 32 + m * 16 + (lane & 15);
      a[m] = *(const s16x8*)(&As[cur][row * 32 + ((lc ^ ((row >> 1) & 3)) * 8)]);
    }
#pragma unroll
    for (int n = 0; n < 8; ++n) {
      int row = n * 16 + (lane & 15);
      b[n] = *(const s16x8*)(&Bs[cur][row * 32 + ((lc ^ ((row >> 1) & 3)) * 8)]);
    }
#pragma unroll
    for (int m = 0; m < 2; ++m)
#pragma unroll
      for (int n = 0; n < 8; ++n)
        acc[m][n] = __builtin_amdgcn_mfma_f32_16x16x32_bf16(a[m], b[n], acc[m][n], 0, 0, 0);
    __syncthreads();  // drains stage(nk) + orders LDS reuse
    cur ^= 1;
  }
  int g4 = lane >> 4, cl = lane & 15;
#pragma unroll
  for (int m = 0; m < 2; ++m) {
#pragma unroll
    for (int j = 0; j < 4; ++j) {
      int rloc = w * 32 + m * 16 + g4 * 4 + j;
      if (r0 + rloc < ne) {
        unsigned short* hp = H + (size_t)toks[rloc] * F_DIM + ft * 64 + cl;
#pragma unroll
        for (int n = 0; n < 4; ++n) {
          float c1 = acc[m][n][j], c3 = acc[m][n + 4][j];
          float h = c1 / (1.0f + __expf(-c1)) * c3;
          __builtin_nontemporal_store(f2bf(h), hp + n * 16);  // don't evict weights
        }
      }
    }
  }
}

// ---------------- GEMM2: out += w * (He @ W2e), 2-phase pipelined ----------------
__global__ __launch_bounds__(256, 3) void gemm2_kernel(
    const unsigned short* __restrict__ H, const unsigned short* __restrict__ w2t,
    const int* __restrict__ cnt, const int* __restrict__ ilist,
    const float* __restrict__ wlist, float* __restrict__ out) {
  int flat = blockIdx.x;                   // 4096 blocks
  int W = (flat & 7) * 512 + (flat >> 3);
  int rt = W & 63;
  int p = W >> 6;
  int n0i = p & 7;
  int e = p >> 3;                          // expert == XCD
  int ne = cnt[e];
  int r0 = rt * 128;
  if (r0 >= ne) return;
  int n0 = n0i * 128;
  __shared__ __align__(16) unsigned short As[2][128 * 32];
  __shared__ __align__(16) unsigned short Bs[2][128 * 32];
  __shared__ int toks[128];
  __shared__ float wts[128];
  int tid = threadIdx.x, lane = tid & 63, w = tid >> 6;
  if (tid < 128) {
    int idx = e * T_TOK + min(r0 + tid, ne - 1);
    toks[tid] = ilist[idx];
    wts[tid] = wlist[idx];
  }
  __syncthreads();
  const unsigned short* bpanel = w2t + ((size_t)e * D_DIM + n0) * F_DIM;
  int sr0 = w * 32 + (lane >> 2);
  int sr1 = sr0 + 16;
  int ch0 = (((lane & 3) ^ ((sr0 >> 1) & 3)) * 8);
  int ch1 = (((lane & 3) ^ ((sr1 >> 1) & 3)) * 8);
  const unsigned short* asrc0 = H + (size_t)toks[sr0] * F_DIM + ch0;
  const unsigned short* asrc1 = H + (size_t)toks[sr1] * F_DIM + ch1;
  const unsigned short* bsrc0 = bpanel + (size_t)sr0 * F_DIM + ch0;
  const unsigned short* bsrc1 = bpanel + (size_t)sr1 * F_DIM + ch1;
  int d0 = (w * 2 + 0) * 512 + lane * 8;
  int d1 = (w * 2 + 1) * 512 + lane * 8;
  f32x4 acc[4][4] = {};
  int wr = w >> 1, wc = w & 1;
  async16(asrc0, &As[0][d0]); async16(bsrc0, &Bs[0][d0]);
  async16(asrc1, &As[0][d1]); async16(bsrc1, &Bs[0][d1]);
  __syncthreads();
  int cur = 0;
  for (int k0 = 0; k0 < F_DIM; k0 += 32) {
    int nk = k0 + 32;
    if (nk < F_DIM) {
      async16(asrc0 + nk, &As[cur ^ 1][d0]); async16(bsrc0 + nk, &Bs[cur ^ 1][d0]);
      async16(asrc1 + nk, &As[cur ^ 1][d1]); async16(bsrc1 + nk, &Bs[cur ^ 1][d1]);
    }
    int lc = lane >> 4;
    s16x8 a[4], b[4];
#pragma unroll
    for (int m = 0; m < 4; ++m) {
      int row = wr * 64 + m * 16 + (lane & 15);
      a[m] = *(const s16x8*)(&As[cur][row * 32 + ((lc ^ ((row >> 1) & 3)) * 8)]);
    }
#pragma unroll
    for (int n = 0; n < 4; ++n) {
      int row = wc * 64 + n * 16 + (lane & 15);
      b[n] = *(const s16x8*)(&Bs[cur][row * 32 + ((lc ^ ((row >> 1) & 3)) * 8)]);
    }
#pragma unroll
    for (int m = 0; m < 4; ++m)
#pragma unroll
      for (int n = 0; n < 4; ++n)
        acc[m][n] = __builtin_amdgcn_mfma_f32_16x16x32_bf16(a[m], b[n], acc[m][n], 0, 0, 0);
    __syncthreads();
    cur ^= 1;
  }
  int g4 = lane >> 4, cl = lane & 15;
#pragma unroll
  for (int m = 0; m < 4; ++m) {
#pragma unroll
    for (int j = 0; j < 4; ++j) {
      int rloc = wr * 64 + m * 16 + g4 * 4 + j;
      if (r0 + rloc < ne) {
        int tok = toks[rloc] >> 1;
        float ww = wts[rloc];
        float* op = out + (size_t)tok * D_DIM + n0 + wc * 64 + cl;
#pragma unroll
        for (int n = 0; n < 4; ++n)
          unsafeAtomicAdd(op + n * 16, ww * acc[m][n][j]);
      }
    }
  }
}

extern "C" void kernel_launch(void* const* d_in, const int* in_sizes, int n_in,
                              void* d_out, int out_size, void* d_ws, size_t ws_size,
                              hipStream_t stream) {
  const float* hs = (const float*)d_in[0];
  const float* nw = (const float*)d_in[1];
  const float* gw = (const float*)d_in[2];
  const float* w1 = (const float*)d_in[3];
  const float* w3 = (const float*)d_in[4];
  const float* w2 = (const float*)d_in[5];
  float* out = (float*)d_out;
  float* logits_out = out + (size_t)T_TOK * D_DIM;

  char* ws = (char*)d_ws;
  unsigned short* xb   = (unsigned short*)(ws);                 // 16 MiB bf16 x
  unsigned short* w13t = (unsigned short*)(ws + 16777216ull);   // 128 MiB [E][64][128][D]
  unsigned short* w2t  = (unsigned short*)(ws + 150994944ull);  // 64 MiB [E][D][F]
  unsigned short* H    = (unsigned short*)(ws + 218103808ull);  // 128 MiB [2T][F]
  int*   ilist = (int*)(ws + 352321536ull);                     // [E][T] int
  float* wlist = (float*)(ws + 352583680ull);                   // [E][T] f32
  int*   cnt   = (int*)(ws + 352845824ull);                     // [E] int

  hipMemsetAsync(d_out, 0, (size_t)out_size * sizeof(float), stream);
  hipMemsetAsync(cnt, 0, E_NUM * sizeof(int), stream);
  norm_router_kernel<<<T_TOK, 256, 0, stream>>>(hs, nw, gw, xb, logits_out, cnt, ilist, wlist);
  transpose_cvt_kernel<<<3 * E_NUM * 1024, 256, 0, stream>>>(w1, w3, w2, w13t, w2t);
  gemm1_kernel<<<E_NUM * 64 * 64, 256, 0, stream>>>(xb, w13t, H, cnt, ilist);
  gemm2_kernel<<<E_NUM * 64 * 8, 256, 0, stream>>>(H, w2t, cnt, ilist, wlist, out);
}

// Round 3
// 939.110 us; speedup vs baseline: 1.2731x; 1.0294x over previous
//
#include <hip/hip_runtime.h>
#include <hip/hip_bf16.h>

#define T_TOK 8192
#define D_DIM 1024
#define F_DIM 4096
#define E_NUM 8

typedef short s16x8 __attribute__((ext_vector_type(8)));
typedef float f32x4 __attribute__((ext_vector_type(4)));
typedef unsigned short u16x8 __attribute__((ext_vector_type(8)));

__device__ __forceinline__ unsigned short f2bf(float f) {
  union { float f; unsigned int u; } v; v.f = f;
  unsigned int u = v.u;
  return (unsigned short)((u + 0x7FFFu + ((u >> 16) & 1u)) >> 16);  // RNE
}

__device__ __forceinline__ void async16(const void* g, void* l) {
  __builtin_amdgcn_global_load_lds((const __attribute__((address_space(1))) void*)g,
                                   (__attribute__((address_space(3))) void*)l, 16, 0, 0);
}

// ---------------- RMSNorm + router (fp32) + top-2 compaction ----------------
__global__ __launch_bounds__(256) void norm_router_kernel(
    const float* __restrict__ hs, const float* __restrict__ nw,
    const float* __restrict__ gw, unsigned short* __restrict__ xb,
    float* __restrict__ logits_out, int* __restrict__ cnt,
    int* __restrict__ ilist, float* __restrict__ wlist) {
  int t = blockIdx.x;
  int tid = threadIdx.x;
  int lane = tid & 63, wid = tid >> 6;
  float4 v = ((const float4*)(hs + (size_t)t * D_DIM))[tid];
  float ss = v.x * v.x + v.y * v.y + v.z * v.z + v.w * v.w;
#pragma unroll
  for (int o = 32; o > 0; o >>= 1) ss += __shfl_xor(ss, o);
  __shared__ float red[4];
  __shared__ float pl[4][8];
  if (lane == 0) red[wid] = ss;
  __syncthreads();
  float ms = (red[0] + red[1] + red[2] + red[3]) * (1.0f / 1024.0f);
  float rs = rsqrtf(ms + 1e-6f);
  float4 wv = ((const float4*)nw)[tid];
  float x0 = v.x * rs * wv.x, x1 = v.y * rs * wv.y;
  float x2 = v.z * rs * wv.z, x3 = v.w * rs * wv.w;
  ((ushort4*)(xb + (size_t)t * D_DIM))[tid] =
      make_ushort4(f2bf(x0), f2bf(x1), f2bf(x2), f2bf(x3));
  float p[8];
#pragma unroll
  for (int e = 0; e < 8; ++e) {
    float4 g = ((const float4*)(gw + (size_t)e * D_DIM))[tid];
    p[e] = x0 * g.x + x1 * g.y + x2 * g.z + x3 * g.w;
  }
#pragma unroll
  for (int e = 0; e < 8; ++e) {
#pragma unroll
    for (int o = 32; o > 0; o >>= 1) p[e] += __shfl_xor(p[e], o);
  }
  if (lane == 0) {
#pragma unroll
    for (int e = 0; e < 8; ++e) pl[wid][e] = p[e];
  }
  __syncthreads();
  if (tid == 0) {
    float l[8];
#pragma unroll
    for (int e = 0; e < 8; ++e) {
      l[e] = pl[0][e] + pl[1][e] + pl[2][e] + pl[3][e];
      logits_out[(size_t)t * 8 + e] = l[e];
    }
    int i0 = 0; float b0 = l[0];
#pragma unroll
    for (int e = 1; e < 8; ++e) if (l[e] > b0) { b0 = l[e]; i0 = e; }
    int i1 = (i0 == 0) ? 1 : 0; float b1 = l[i1];
#pragma unroll
    for (int e = 0; e < 8; ++e) if (e != i0 && l[e] > b1) { b1 = l[e]; i1 = e; }
    float wa = 1.0f / (1.0f + __expf(b1 - b0));
    float wb = 1.0f / (1.0f + __expf(b0 - b1));
    int p0 = atomicAdd(&cnt[i0], 1);
    ilist[i0 * T_TOK + p0] = t * 2;     wlist[i0 * T_TOK + p0] = wa;
    int p1 = atomicAdd(&cnt[i1], 1);
    ilist[i1 * T_TOK + p1] = t * 2 + 1; wlist[i1 * T_TOK + p1] = wb;
  }
}

// ---- weight f32 -> bf16 transpose. w1/w3 -> interleaved w13t[e][ft][128][D];
// ---- w2 -> w2t[e][D][F]
__global__ __launch_bounds__(256) void transpose_cvt_kernel(
    const float* __restrict__ w1, const float* __restrict__ w3,
    const float* __restrict__ w2, unsigned short* __restrict__ w13t,
    unsigned short* __restrict__ w2t) {
  __shared__ unsigned short tileS[64][72];  // [c-local][r-local], padded
  int bx = blockIdx.x;
  int tensor = bx >> 13;
  int e = (bx >> 10) & 7;
  int tl = bx & 1023;
  const float* src; int C, tr, tc;
  if (tensor == 0) {
    src = w1 + (size_t)e * D_DIM * F_DIM; C = F_DIM; tr = tl >> 6; tc = tl & 63;
  } else if (tensor == 1) {
    src = w3 + (size_t)e * D_DIM * F_DIM; C = F_DIM; tr = tl >> 6; tc = tl & 63;
  } else {
    src = w2 + (size_t)e * F_DIM * D_DIM; C = D_DIM; tr = tl >> 4; tc = tl & 15;
  }
  int r0 = tr * 64, c0 = tc * 64;
  int tid = threadIdx.x;
  int rr = tid >> 4, ccb = (tid & 15) * 4;
#pragma unroll
  for (int i = 0; i < 4; ++i) {
    int r = rr + i * 16;
    float4 v = *(const float4*)(src + (size_t)(r0 + r) * C + c0 + ccb);
    tileS[ccb + 0][r] = f2bf(v.x);
    tileS[ccb + 1][r] = f2bf(v.y);
    tileS[ccb + 2][r] = f2bf(v.z);
    tileS[ccb + 3][r] = f2bf(v.w);
  }
  __syncthreads();
  int row = tid >> 2, col = (tid & 3) * 16;
  unsigned short* dp;
  if (tensor < 2) {
    int f = c0 + row;
    int prow = ((f >> 6) * 128) + (f & 63) + (tensor == 1 ? 64 : 0);
    dp = w13t + ((size_t)e * 8192 + prow) * D_DIM + r0 + col;
  } else {
    dp = w2t + ((size_t)e * D_DIM + c0 + row) * F_DIM + r0 + col;
  }
  u16x8 v0, v1;
#pragma unroll
  for (int j = 0; j < 8; ++j) { v0[j] = tileS[row][col + j]; v1[j] = tileS[row][col + 8 + j]; }
  *(u16x8*)dp = v0;
  *(u16x8*)(dp + 8) = v1;
}

// ---- GEMM1: H = silu(Xe@W1e) * (Xe@W3e), depth-2 counted-vmcnt pipeline ----
__global__ __launch_bounds__(256, 3) void gemm1_kernel(
    const unsigned short* __restrict__ xb, const unsigned short* __restrict__ w13t,
    unsigned short* __restrict__ H, const int* __restrict__ cnt,
    const int* __restrict__ ilist) {
  int flat = blockIdx.x;                    // 32768 blocks
  int W = (flat & 7) * 4096 + (flat >> 3);  // XCD-contiguous work chunks
  int rt = W & 63;
  int p = W >> 6;
  int ft = p & 63;
  int e = p >> 6;                           // expert == XCD
  int ne = cnt[e];
  int r0 = rt * 128;
  if (r0 >= ne) return;
  __shared__ __align__(16) unsigned short As[3 * 4096];
  __shared__ __align__(16) unsigned short Bs[3 * 4096];
  __shared__ int toks[128];
  int tid = threadIdx.x, lane = tid & 63, w = tid >> 6;
  if (tid < 128) toks[tid] = ilist[e * T_TOK + min(r0 + tid, ne - 1)];
  __syncthreads();
  const unsigned short* bpanel = w13t + ((size_t)(e * 64 + ft) * 128) * D_DIM;
  int sr0 = w * 32 + (lane >> 2);
  int sr1 = sr0 + 16;
  int ch0 = (((lane & 3) ^ ((sr0 >> 1) & 3)) * 8);
  int ch1 = (((lane & 3) ^ ((sr1 >> 1) & 3)) * 8);
  const unsigned short* asrc0 = xb + (size_t)(toks[sr0] >> 1) * D_DIM + ch0;
  const unsigned short* asrc1 = xb + (size_t)(toks[sr1] >> 1) * D_DIM + ch1;
  const unsigned short* bsrc0 = bpanel + (size_t)sr0 * D_DIM + ch0;
  const unsigned short* bsrc1 = bpanel + (size_t)sr1 * D_DIM + ch1;
  int d0 = (w * 2 + 0) * 512 + lane * 8;
  int d1 = (w * 2 + 1) * 512 + lane * 8;
  f32x4 acc[2][8] = {};
  // prologue: stage tiles 0,1 into buffers 0,1 (8 loads outstanding per wave)
  async16(asrc0, &As[d0]); async16(bsrc0, &Bs[d0]);
  async16(asrc1, &As[d1]); async16(bsrc1, &Bs[d1]);
  async16(asrc0 + 32, &As[4096 + d0]); async16(bsrc0 + 32, &Bs[4096 + d0]);
  async16(asrc1 + 32, &As[4096 + d1]); async16(bsrc1 + 32, &Bs[4096 + d1]);
  int bt = 0;
  for (int t = 0; t < 32; ++t) {
    // wait own tile-t loads (counted: never drain the t+1 prefetch), then barrier
    if (t < 31) asm volatile("s_waitcnt vmcnt(4)" ::: "memory");
    else        asm volatile("s_waitcnt vmcnt(0)" ::: "memory");
    __builtin_amdgcn_s_barrier();
    if (t + 2 < 32) {  // stage t+2 into the buffer last read at t-1 (freed by barrier)
      int nb = bt + 2; if (nb >= 3) nb -= 3;
      int nk = (t + 2) * 32;
      async16(asrc0 + nk, &As[nb * 4096 + d0]); async16(bsrc0 + nk, &Bs[nb * 4096 + d0]);
      async16(asrc1 + nk, &As[nb * 4096 + d1]); async16(bsrc1 + nk, &Bs[nb * 4096 + d1]);
    }
    const unsigned short* Ab = &As[bt * 4096];
    const unsigned short* Bb = &Bs[bt * 4096];
    int lc = lane >> 4;
    s16x8 a[2], b[8];
#pragma unroll
    for (int m = 0; m < 2; ++m) {
      int row = w * 32 + m * 16 + (lane & 15);
      a[m] = *(const s16x8*)(&Ab[row * 32 + ((lc ^ ((row >> 1) & 3)) * 8)]);
    }
#pragma unroll
    for (int n = 0; n < 8; ++n) {
      int row = n * 16 + (lane & 15);
      b[n] = *(const s16x8*)(&Bb[row * 32 + ((lc ^ ((row >> 1) & 3)) * 8)]);
    }
#pragma unroll
    for (int m = 0; m < 2; ++m)
#pragma unroll
      for (int n = 0; n < 8; ++n)
        acc[m][n] = __builtin_amdgcn_mfma_f32_16x16x32_bf16(a[m], b[n], acc[m][n], 0, 0, 0);
    if (++bt == 3) bt = 0;
  }
  int g4 = lane >> 4, cl = lane & 15;
#pragma unroll
  for (int m = 0; m < 2; ++m) {
#pragma unroll
    for (int j = 0; j < 4; ++j) {
      int rloc = w * 32 + m * 16 + g4 * 4 + j;
      if (r0 + rloc < ne) {
        unsigned short* hp = H + (size_t)toks[rloc] * F_DIM + ft * 64 + cl;
#pragma unroll
        for (int n = 0; n < 4; ++n) {
          float c1 = acc[m][n][j], c3 = acc[m][n + 4][j];
          float h = c1 / (1.0f + __expf(-c1)) * c3;
          hp[n * 16] = f2bf(h);
        }
      }
    }
  }
}

// ---- GEMM2: out += w * (He @ W2e), depth-2 counted-vmcnt pipeline ----
__global__ __launch_bounds__(256, 3) void gemm2_kernel(
    const unsigned short* __restrict__ H, const unsigned short* __restrict__ w2t,
    const int* __restrict__ cnt, const int* __restrict__ ilist,
    const float* __restrict__ wlist, float* __restrict__ out) {
  int flat = blockIdx.x;                   // 4096 blocks
  int W = (flat & 7) * 512 + (flat >> 3);
  int rt = W & 63;
  int p = W >> 6;
  int n0i = p & 7;
  int e = p >> 3;                          // expert == XCD
  int ne = cnt[e];
  int r0 = rt * 128;
  if (r0 >= ne) return;
  int n0 = n0i * 128;
  __shared__ __align__(16) unsigned short As[3 * 4096];
  __shared__ __align__(16) unsigned short Bs[3 * 4096];
  __shared__ int toks[128];
  __shared__ float wts[128];
  int tid = threadIdx.x, lane = tid & 63, w = tid >> 6;
  if (tid < 128) {
    int idx = e * T_TOK + min(r0 + tid, ne - 1);
    toks[tid] = ilist[idx];
    wts[tid] = wlist[idx];
  }
  __syncthreads();
  const unsigned short* bpanel = w2t + ((size_t)e * D_DIM + n0) * F_DIM;
  int sr0 = w * 32 + (lane >> 2);
  int sr1 = sr0 + 16;
  int ch0 = (((lane & 3) ^ ((sr0 >> 1) & 3)) * 8);
  int ch1 = (((lane & 3) ^ ((sr1 >> 1) & 3)) * 8);
  const unsigned short* asrc0 = H + (size_t)toks[sr0] * F_DIM + ch0;
  const unsigned short* asrc1 = H + (size_t)toks[sr1] * F_DIM + ch1;
  const unsigned short* bsrc0 = bpanel + (size_t)sr0 * F_DIM + ch0;
  const unsigned short* bsrc1 = bpanel + (size_t)sr1 * F_DIM + ch1;
  int d0 = (w * 2 + 0) * 512 + lane * 8;
  int d1 = (w * 2 + 1) * 512 + lane * 8;
  f32x4 acc[4][4] = {};
  int wr = w >> 1, wc = w & 1;
  async16(asrc0, &As[d0]); async16(bsrc0, &Bs[d0]);
  async16(asrc1, &As[d1]); async16(bsrc1, &Bs[d1]);
  async16(asrc0 + 32, &As[4096 + d0]); async16(bsrc0 + 32, &Bs[4096 + d0]);
  async16(asrc1 + 32, &As[4096 + d1]); async16(bsrc1 + 32, &Bs[4096 + d1]);
  int bt = 0;
  for (int t = 0; t < 128; ++t) {
    if (t < 127) asm volatile("s_waitcnt vmcnt(4)" ::: "memory");
    else         asm volatile("s_waitcnt vmcnt(0)" ::: "memory");
    __builtin_amdgcn_s_barrier();
    if (t + 2 < 128) {
      int nb = bt + 2; if (nb >= 3) nb -= 3;
      int nk = (t + 2) * 32;
      async16(asrc0 + nk, &As[nb * 4096 + d0]); async16(bsrc0 + nk, &Bs[nb * 4096 + d0]);
      async16(asrc1 + nk, &As[nb * 4096 + d1]); async16(bsrc1 + nk, &Bs[nb * 4096 + d1]);
    }
    const unsigned short* Ab = &As[bt * 4096];
    const unsigned short* Bb = &Bs[bt * 4096];
    int lc = lane >> 4;
    s16x8 a[4], b[4];
#pragma unroll
    for (int m = 0; m < 4; ++m) {
      int row = wr * 64 + m * 16 + (lane & 15);
      a[m] = *(const s16x8*)(&Ab[row * 32 + ((lc ^ ((row >> 1) & 3)) * 8)]);
    }
#pragma unroll
    for (int n = 0; n < 4; ++n) {
      int row = wc * 64 + n * 16 + (lane & 15);
      b[n] = *(const s16x8*)(&Bb[row * 32 + ((lc ^ ((row >> 1) & 3)) * 8)]);
    }
#pragma unroll
    for (int m = 0; m < 4; ++m)
#pragma unroll
      for (int n = 0; n < 4; ++n)
        acc[m][n] = __builtin_amdgcn_mfma_f32_16x16x32_bf16(a[m], b[n], acc[m][n], 0, 0, 0);
    if (++bt == 3) bt = 0;
  }
  int g4 = lane >> 4, cl = lane & 15;
#pragma unroll
  for (int m = 0; m < 4; ++m) {
#pragma unroll
    for (int j = 0; j < 4; ++j) {
      int rloc = wr * 64 + m * 16 + g4 * 4 + j;
      if (r0 + rloc < ne) {
        int tok = toks[rloc] >> 1;
        float ww = wts[rloc];
        float* op = out + (size_t)tok * D_DIM + n0 + wc * 64 + cl;
#pragma unroll
        for (int n = 0; n < 4; ++n)
          unsafeAtomicAdd(op + n * 16, ww * acc[m][n][j]);
      }
    }
  }
}

extern "C" void kernel_launch(void* const* d_in, const int* in_sizes, int n_in,
                              void* d_out, int out_size, void* d_ws, size_t ws_size,
                              hipStream_t stream) {
  const float* hs = (const float*)d_in[0];
  const float* nw = (const float*)d_in[1];
  const float* gw = (const float*)d_in[2];
  const float* w1 = (const float*)d_in[3];
  const float* w3 = (const float*)d_in[4];
  const float* w2 = (const float*)d_in[5];
  float* out = (float*)d_out;
  float* logits_out = out + (size_t)T_TOK * D_DIM;

  char* ws = (char*)d_ws;
  unsigned short* xb   = (unsigned short*)(ws);                 // 16 MiB bf16 x
  unsigned short* w13t = (unsigned short*)(ws + 16777216ull);   // 128 MiB [E][64][128][D]
  unsigned short* w2t  = (unsigned short*)(ws + 150994944ull);  // 64 MiB [E][D][F]
  unsigned short* H    = (unsigned short*)(ws + 218103808ull);  // 128 MiB [2T][F]
  int*   ilist = (int*)(ws + 352321536ull);                     // [E][T] int
  float* wlist = (float*)(ws + 352583680ull);                   // [E][T] f32
  int*   cnt   = (int*)(ws + 352845824ull);                     // [E] int

  hipMemsetAsync(d_out, 0, (size_t)out_size * sizeof(float), stream);
  hipMemsetAsync(cnt, 0, E_NUM * sizeof(int), stream);
  norm_router_kernel<<<T_TOK, 256, 0, stream>>>(hs, nw, gw, xb, logits_out, cnt, ilist, wlist);
  transpose_cvt_kernel<<<3 * E_NUM * 1024, 256, 0, stream>>>(w1, w3, w2, w13t, w2t);
  gemm1_kernel<<<E_NUM * 64 * 64, 256, 0, stream>>>(xb, w13t, H, cnt, ilist);
  gemm2_kernel<<<E_NUM * 64 * 8, 256, 0, stream>>>(H, w2t, cnt, ilist, wlist, out);
}